// Round 10
// baseline (293.655 us; speedup 1.0000x reference)
//
#include <hip/hip_runtime.h>
#include <hip/hip_bf16.h>

// LSTM block, fused. Inputs fp32, outputs fp32. bf16 MFMA internally.
// r7 skeleton + A-prefetch via global_load_lds DMA (raw fp32 in LDS, zero
// register cost, depth = 1 full tile). Read-side cvt to bf16 (asm cvt_pk).
// Weights in registers (Breg 128 VGPR/wave, gate-interleaved). One barrier
// per 32-row tile with lgkmcnt(0) vmcnt(16) (A-DMA retired, c-loads/stores
// stay in flight). LDS 80KB: A fp32 dbuf 2x32K + c_ex dbuf 2x8K.

typedef __attribute__((ext_vector_type(8))) short bf16x8;   // 8 bf16 = 4 VGPRs
typedef __attribute__((ext_vector_type(4))) float f32x4;

static __device__ __forceinline__ unsigned short f2bf(float f) {
    unsigned int u = __builtin_bit_cast(unsigned int, f);
    u += 0x7FFFu + ((u >> 16) & 1u);      // RNE
    return (unsigned short)(u >> 16);
}

static __device__ __forceinline__ unsigned int cvtpk(float lo, float hi) {
    unsigned int r;
    asm("v_cvt_pk_bf16_f32 %0, %1, %2" : "=v"(r) : "v"(lo), "v"(hi));
    return r;
}

static __device__ __forceinline__ bf16x8 cvt8(f32x4 a, f32x4 b) {
    union { bf16x8 v; unsigned int w[4]; } r;
    r.w[0] = cvtpk(a[0], a[1]);
    r.w[1] = cvtpk(a[2], a[3]);
    r.w[2] = cvtpk(b[0], b[1]);
    r.w[3] = cvtpk(b[2], b[3]);
    return r.v;
}

static __device__ __forceinline__ float fsig(float x) {
    float e = __builtin_amdgcn_exp2f(-1.44269504f * x);
    return __builtin_amdgcn_rcpf(1.0f + e);
}
static __device__ __forceinline__ float ftanh(float x) {
    float e = __builtin_amdgcn_exp2f(2.8853900818f * x);
    return 1.0f - 2.0f * __builtin_amdgcn_rcpf(e + 1.0f);
}

static __device__ __forceinline__ void gload16(const void* gsrc, void* ldst) {
    __builtin_amdgcn_global_load_lds(
        (const __attribute__((address_space(1))) unsigned int*)gsrc,
        (__attribute__((address_space(3))) unsigned int*)ldst,
        16, 0, 0);
}

#define MEMFENCE asm volatile("" ::: "memory")

// ---------------- weight prep: fragment-linear bf16, 16-col gate interleave ----
// WgF: 256 frags of 1KB, frag index = ks*32 + wn*4 + g  (ks 0..7, wn 0..7, g 0..3)
//   lane l: within-gate col = wn*16 + (l&15), k = ks*32 + (l>>4)*8 .. +8
// WchF: 32 frags, index = kt*8 + wn: col = wn*16 + (l&15), k = kt*32 + (l>>4)*8
__global__ void prep_weights(const float* __restrict__ Wf, const float* __restrict__ Wi,
                             const float* __restrict__ Wc, const float* __restrict__ Wo,
                             const float* __restrict__ Wch,
                             unsigned short* __restrict__ WgF,   // 512*256
                             unsigned short* __restrict__ WchF)  // 128*128
{
    int u = blockIdx.x * 256 + threadIdx.x;
    if (u < 16384) {
        int lane = u & 63, g = (u >> 6) & 3, wn = (u >> 8) & 7, ks = u >> 11;
        int l15 = lane & 15, lg = lane >> 4;
        int cg = wn * 16 + l15;
        int k0 = ks * 32 + lg * 8;
        const float* W = (g == 0) ? Wf : (g == 1) ? Wi : (g == 2) ? Wc : Wo;
        union { bf16x8 v; unsigned short s[8]; } r;
#pragma unroll
        for (int i = 0; i < 8; ++i) r.s[i] = f2bf(W[(size_t)(k0 + i) * 128 + cg]);
        *(bf16x8*)(WgF + (size_t)u * 8) = r.v;
    } else if (u < 16384 + 2048) {
        int u2 = u - 16384;
        int lane = u2 & 63, wn = (u2 >> 6) & 7, kt = u2 >> 9;
        int l15 = lane & 15, lg = lane >> 4;
        int col = wn * 16 + l15, k0 = kt * 32 + lg * 8;
        union { bf16x8 v; unsigned short s[8]; } r;
#pragma unroll
        for (int i = 0; i < 8; ++i) r.s[i] = f2bf(Wch[(size_t)(k0 + i) * 128 + col]);
        *(bf16x8*)(WchF + (size_t)u2 * 8) = r.v;
    }
}

// One 32-row tile. CUR = compile-time parity; CIN/COUT = c-input ping-pong.
#define TILE_BODY(T, CUR, CIN, COUT)                                            \
  do {                                                                          \
    const long m0 = base + (long)(T) * 32;                                      \
    /* step1: DMA A(t+1) raw fp32 -> LDS buf CUR^1 (zero register cost) */      \
    if ((T) < 31) {                                                             \
      char* ad = lds + ((CUR) ^ 1) * 32768;                                     \
      _Pragma("unroll")                                                         \
      for (int j = 0; j < 4; ++j)                                               \
        gload16(srcT + (m0 + 32 + wv + j * 8) * 128, ad + (j * 512 + tid) * 16);\
    }                                                                           \
    MEMFENCE;                                                                   \
    /* step2: c loads for tile (T)+1 */                                         \
    if ((T) < 31) {                                                             \
      _Pragma("unroll")                                                         \
      for (int am = 0; am < 2; ++am)                                            \
        _Pragma("unroll")                                                       \
        for (int r = 0; r < 4; ++r)                                             \
          COUT[am * 4 + r] = cg[(m0 + 32 + am * 16 + lg * 4 + r) * 128 + colc]; \
    }                                                                           \
    /* step3: gates MFMA -- A fp32 from LDS buf CUR (cvt on read), B in regs */ \
    {                                                                           \
      const char* ab = lds + (CUR) * 32768;                                     \
      _Pragma("unroll")                                                         \
      for (int ks = 0; ks < 8; ++ks) {                                          \
        const int v0 = ks * 8 + lg * 2;                                         \
        f32x4 p00 = *(const f32x4*)(ab + l15 * 1024        + (((v0    ) ^ xr) << 4)); \
        f32x4 p01 = *(const f32x4*)(ab + l15 * 1024        + (((v0 + 1) ^ xr) << 4)); \
        f32x4 p10 = *(const f32x4*)(ab + (16 + l15) * 1024 + (((v0    ) ^ xr) << 4)); \
        f32x4 p11 = *(const f32x4*)(ab + (16 + l15) * 1024 + (((v0 + 1) ^ xr) << 4)); \
        bf16x8 af0 = cvt8(p00, p01);                                            \
        bf16x8 af1 = cvt8(p10, p11);                                            \
        _Pragma("unroll")                                                       \
        for (int g_ = 0; g_ < 4; ++g_) {                                        \
          acc[0][g_] = __builtin_amdgcn_mfma_f32_16x16x32_bf16(af0, Breg[ks][g_], acc[0][g_], 0, 0, 0); \
          acc[1][g_] = __builtin_amdgcn_mfma_f32_16x16x32_bf16(af1, Breg[ks][g_], acc[1][g_], 0, 0, 0); \
        }                                                                       \
      }                                                                         \
    }                                                                           \
    /* step4: elementwise -> c_new; store c; bf16 exchange to c_ex buf CUR */   \
    char* cex = lds + 65536 + (CUR) * 8192;                                     \
    _Pragma("unroll")                                                           \
    for (int am = 0; am < 2; ++am)                                              \
      _Pragma("unroll")                                                         \
      for (int r = 0; r < 4; ++r) {                                             \
        float f_  = fsig(acc[am][0][r] + bfb);                                  \
        float i_  = fsig(acc[am][1][r] + bib);                                  \
        float ct_ = ftanh(acc[am][2][r] + bcb);                                 \
        float cv_ = f_ * CIN[am * 4 + r] + i_ * ct_;                            \
        coutp[(m0 + am * 16 + lg * 4 + r) * 128 + colc] = cv_;                  \
        *(unsigned short*)(cex + (am * 4 + (wn >> 1)) * 1024                    \
             + (cslotbase + lg * 4 + r) * 16 + (l15 & 7) * 2) = f2bf(cv_);      \
      }                                                                         \
    /* step6: one barrier; A-DMA retired (vmcnt 16 newest = c-loads+c-stores) */\
    asm volatile("s_waitcnt lgkmcnt(0) vmcnt(16)" ::: "memory");                \
    __builtin_amdgcn_s_barrier();                                               \
    __builtin_amdgcn_sched_barrier(0);                                          \
    /* step7: GEMM2 (c_ex x Wch-regs) + h epilogue */                           \
    {                                                                           \
      f32x4 acc2_0 = {0.f,0.f,0.f,0.f}, acc2_1 = {0.f,0.f,0.f,0.f};             \
      _Pragma("unroll")                                                         \
      for (int kt = 0; kt < 4; ++kt) {                                          \
        bf16x8 p0 = *(const bf16x8*)(cex + kt * 1024 + lane * 16);              \
        bf16x8 p1 = *(const bf16x8*)(cex + (4 + kt) * 1024 + lane * 16);        \
        acc2_0 = __builtin_amdgcn_mfma_f32_16x16x32_bf16(p0, Wreg[kt], acc2_0, 0, 0, 0); \
        acc2_1 = __builtin_amdgcn_mfma_f32_16x16x32_bf16(p1, Wreg[kt], acc2_1, 0, 0, 0); \
      }                                                                         \
      _Pragma("unroll")                                                         \
      for (int r = 0; r < 4; ++r) {                                             \
        float o0 = fsig(acc[0][3][r] + bob);                                    \
        houtp[(m0 +      lg * 4 + r) * 128 + colc] = o0 * ftanh(acc2_0[r] + bchb); \
        float o1 = fsig(acc[1][3][r] + bob);                                    \
        houtp[(m0 + 16 + lg * 4 + r) * 128 + colc] = o1 * ftanh(acc2_1[r] + bchb); \
      }                                                                         \
    }                                                                           \
    _Pragma("unroll")                                                           \
    for (int am = 0; am < 2; ++am)                                              \
      _Pragma("unroll")                                                         \
      for (int g_ = 0; g_ < 4; ++g_) acc[am][g_] = (f32x4){0.f,0.f,0.f,0.f};    \
  } while (0)

// ---------------- fused kernel: 1024 rows per 512-thread block, 32-row tiles ----
// LDS (80 KB): A fp32 dbuf [0,32K)+[32K,64K); c_ex dbuf [64K,72K)+[72K,80K)
// A layout: LDS[row][u] (16B units u=0..63) = G[row][u ^ (row&7)]; rows 0..31,
// cols 0..127 = x, 128..255 = h. Staged by wave wv: row = j*8 + wv (row&7 == wv).
__global__ __launch_bounds__(512, 2) void lstm_fused(
    const float* __restrict__ xg, const float* __restrict__ hg, const float* __restrict__ cg,
    const float* __restrict__ bfv, const float* __restrict__ biv,
    const float* __restrict__ bcv, const float* __restrict__ bov,
    const float* __restrict__ bchv,
    const unsigned short* __restrict__ WgF, const unsigned short* __restrict__ WchF,
    float* __restrict__ out, int nrows)
{
    __shared__ uint4 lds4[5120];                 // 80 KB
    char* lds = (char*)lds4;

    const int tid  = threadIdx.x;
    const int lane = tid & 63;
    const int wn   = tid >> 6;                   // 0..7: owns cols wn*16..+16 of each gate
    const int wv   = wn;                         // wave index (staging row & 7)
    const int l15  = lane & 15;
    const int lg   = lane >> 4;
    const int xr   = l15 & 7;                    // A-read swizzle key (row&7)
    const long base = (long)blockIdx.x << 10;    // 1024 rows per block

    float* houtp = out;
    float* coutp = out + (size_t)nrows * 128;

    const int colc = wn * 16 + l15;              // lane-local output column
    const float bfb = bfv[colc], bib = biv[colc], bcb = bcv[colc],
                bob = bov[colc], bchb = bchv[colc];
    const int cslotbase = ((wn & 1) * 2 + (l15 >> 3)) * 16;

    // ---- weights into registers (L2-resident source; read once per block)
    bf16x8 Breg[8][4];                           // [ks][gate] : 128 VGPRs
#pragma unroll
    for (int ks = 0; ks < 8; ++ks)
#pragma unroll
        for (int g = 0; g < 4; ++g)
            Breg[ks][g] = *(const bf16x8*)(WgF + (size_t)((ks * 32 + wn * 4 + g) * 512 + lane * 8));
    bf16x8 Wreg[4];                              // [kt] : 16 VGPRs
#pragma unroll
    for (int kt = 0; kt < 4; ++kt)
        Wreg[kt] = *(const bf16x8*)(WchF + (size_t)((kt * 8 + wn) * 512 + lane * 8));

    // ---- A-staging source (pre-swizzled global address; LDS dest stays linear)
    // lane u stages 16B unit u of its row; global unit = u ^ wv (same 1KB row,
    // lanes permuted -> fully coalesced). u<32 -> x half, else h half.
    const int uA  = lane;
    const int upA = uA ^ wv;
    const float* srcT = ((uA < 32) ? xg : hg) + (upA & 31) * 4;

    // ---- prologue: DMA A(0) -> buf0; load c(0) -> c0
#pragma unroll
    for (int j = 0; j < 4; ++j)
        gload16(srcT + (base + wv + j * 8) * 128, lds + (j * 512 + tid) * 16);
    MEMFENCE;
    float c0[8], c1[8];
#pragma unroll
    for (int am = 0; am < 2; ++am)
#pragma unroll
        for (int r = 0; r < 4; ++r)
            c0[am * 4 + r] = cg[(base + am * 16 + lg * 4 + r) * 128 + colc];
    asm volatile("s_waitcnt vmcnt(8)" ::: "memory");   // A-DMA(4) landed; c-loads in flight
    __builtin_amdgcn_s_barrier();

    f32x4 acc[2][4];                             // [am][gate]
#pragma unroll
    for (int am = 0; am < 2; ++am)
#pragma unroll
        for (int g = 0; g < 4; ++g) acc[am][g] = {0.f, 0.f, 0.f, 0.f};

#pragma unroll 1
    for (int t = 0; t < 32; t += 2) {
        TILE_BODY(t,     0, c0, c1);
        TILE_BODY(t + 1, 1, c1, c0);
    }
}

extern "C" void kernel_launch(void* const* d_in, const int* in_sizes, int n_in,
                              void* d_out, int out_size, void* d_ws, size_t ws_size,
                              hipStream_t stream)
{
    const float* x   = (const float*)d_in[0];
    const float* h   = (const float*)d_in[1];
    const float* c   = (const float*)d_in[2];
    const float* Wf  = (const float*)d_in[3];
    const float* bf_ = (const float*)d_in[4];
    const float* Wi  = (const float*)d_in[5];
    const float* bi_ = (const float*)d_in[6];
    const float* Wc  = (const float*)d_in[7];
    const float* bc_ = (const float*)d_in[8];
    const float* Wo  = (const float*)d_in[9];
    const float* bo_ = (const float*)d_in[10];
    const float* Wch = (const float*)d_in[11];
    const float* bch = (const float*)d_in[12];

    unsigned short* WgF  = (unsigned short*)d_ws;         // 512*256 bf16 fragment-linear
    unsigned short* WchF = WgF + 512 * 256;               // 128*128 bf16 fragment-linear
    float* out = (float*)d_out;

    int nrows = in_sizes[0] / 128;                        // 262144

    prep_weights<<<dim3(72), dim3(256), 0, stream>>>(Wf, Wi, Wc, Wo, Wch, WgF, WchF);
    lstm_fused<<<dim3(nrows / 1024), dim3(512), 0, stream>>>(
        x, h, c, bf_, bi_, bc_, bo_, bch, WgF, WchF, out, nrows);
}

// Round 11
// 214.864 us; speedup vs baseline: 1.3667x; 1.3667x over previous
//
#include <hip/hip_runtime.h>
#include <hip/hip_bf16.h>

// LSTM block, fused. Inputs fp32, outputs fp32. bf16 MFMA internally.
// r7 skeleton (weights-in-regs Breg 128/wave, gate-interleaved lane-local
// elementwise, one barrier per 32-row tile) + register-neutral depth-2 A
// prefetch:  c-input via global_load_lds DMA (zero regs), Wch frags per-tile
// from L2 (short live range), A(t+2) loads issued at tile t into named RI/RO
// register pairs (2x-unrolled bodies -> static indices).
// Barrier: s_waitcnt lgkmcnt(0) vmcnt(16)  (c-DMA retired; A+Wch+stores fly).
// LDS 80KB: A bf16 dbuf 2x16K | c fp32 dbuf 2x16K | c_ex dbuf 2x8K.

typedef __attribute__((ext_vector_type(8))) short bf16x8;   // 8 bf16 = 4 VGPRs
typedef __attribute__((ext_vector_type(4))) float f32x4;

static __device__ __forceinline__ unsigned short f2bf(float f) {
    unsigned int u = __builtin_bit_cast(unsigned int, f);
    u += 0x7FFFu + ((u >> 16) & 1u);      // RNE
    return (unsigned short)(u >> 16);
}

static __device__ __forceinline__ unsigned int cvtpk(float lo, float hi) {
    unsigned int r;
    asm("v_cvt_pk_bf16_f32 %0, %1, %2" : "=v"(r) : "v"(lo), "v"(hi));
    return r;
}

static __device__ __forceinline__ bf16x8 cvt8(f32x4 a, f32x4 b) {
    union { bf16x8 v; unsigned int w[4]; } r;
    r.w[0] = cvtpk(a[0], a[1]);
    r.w[1] = cvtpk(a[2], a[3]);
    r.w[2] = cvtpk(b[0], b[1]);
    r.w[3] = cvtpk(b[2], b[3]);
    return r.v;
}

static __device__ __forceinline__ float fsig(float x) {
    float e = __builtin_amdgcn_exp2f(-1.44269504f * x);
    return __builtin_amdgcn_rcpf(1.0f + e);
}
static __device__ __forceinline__ float ftanh(float x) {
    float e = __builtin_amdgcn_exp2f(2.8853900818f * x);
    return 1.0f - 2.0f * __builtin_amdgcn_rcpf(e + 1.0f);
}

static __device__ __forceinline__ void gload16(const void* gsrc, void* ldst) {
    __builtin_amdgcn_global_load_lds(
        (const __attribute__((address_space(1))) unsigned int*)gsrc,
        (__attribute__((address_space(3))) unsigned int*)ldst,
        16, 0, 0);
}

#define MEMFENCE asm volatile("" ::: "memory")

// ---------------- weight prep: fragment-linear bf16, 16-col gate interleave ----
// WgF: 256 frags of 1KB, frag index = ks*32 + wn*4 + g  (ks 0..7, wn 0..7, g 0..3)
//   lane l: within-gate col = wn*16 + (l&15), k = ks*32 + (l>>4)*8 .. +8
// WchF: 32 frags, index = kt*8 + wn: col = wn*16 + (l&15), k = kt*32 + (l>>4)*8
__global__ void prep_weights(const float* __restrict__ Wf, const float* __restrict__ Wi,
                             const float* __restrict__ Wc, const float* __restrict__ Wo,
                             const float* __restrict__ Wch,
                             unsigned short* __restrict__ WgF,   // 512*256
                             unsigned short* __restrict__ WchF)  // 128*128
{
    int u = blockIdx.x * 256 + threadIdx.x;
    if (u < 16384) {
        int lane = u & 63, g = (u >> 6) & 3, wn = (u >> 8) & 7, ks = u >> 11;
        int l15 = lane & 15, lg = lane >> 4;
        int cg = wn * 16 + l15;
        int k0 = ks * 32 + lg * 8;
        const float* W = (g == 0) ? Wf : (g == 1) ? Wi : (g == 2) ? Wc : Wo;
        union { bf16x8 v; unsigned short s[8]; } r;
#pragma unroll
        for (int i = 0; i < 8; ++i) r.s[i] = f2bf(W[(size_t)(k0 + i) * 128 + cg]);
        *(bf16x8*)(WgF + (size_t)u * 8) = r.v;
    } else if (u < 16384 + 2048) {
        int u2 = u - 16384;
        int lane = u2 & 63, wn = (u2 >> 6) & 7, kt = u2 >> 9;
        int l15 = lane & 15, lg = lane >> 4;
        int col = wn * 16 + l15, k0 = kt * 32 + lg * 8;
        union { bf16x8 v; unsigned short s[8]; } r;
#pragma unroll
        for (int i = 0; i < 8; ++i) r.s[i] = f2bf(Wch[(size_t)(k0 + i) * 128 + col]);
        *(bf16x8*)(WchF + (size_t)u2 * 8) = r.v;
    }
}

// One 32-row tile. CUR = compile-time parity. RI* = raw A(T+1) (stage now),
// RO* = receives raw A(T+2).
#define TILE_BODY(T, CUR, RI0,RI1,RI2,RI3, RO0,RO1,RO2,RO3)                     \
  do {                                                                          \
    const long m0 = base + (long)(T) * 32;                                      \
    /* c-DMA for tile T+1 -> cbuf CUR^1 (FIRST vm ops of the body) */           \
    if ((T) < 31) {                                                             \
      char* cd = lds + 32768 + ((CUR) ^ 1) * 16384;                             \
      gload16(cg + (m0 + 32 + (tid >> 5)) * 128 + (tid & 31) * 4, cd + tid * 16);          \
      gload16(cg + (m0 + 48 + (tid >> 5)) * 128 + (tid & 31) * 4, cd + 8192 + tid * 16);   \
    }                                                                           \
    MEMFENCE;                                                                   \
    /* A-loads for tile T+2 -> RO (dummy re-load at T==30 keeps vm count) */    \
    if ((T) < 31) {                                                             \
      const long ar = ((T) < 30) ? (m0 + 64) : m0;                              \
      const float* s_ = asrc + (ar + rowA) * 128;                               \
      RO0 = ((const f32x4*)s_)[0]; RO1 = ((const f32x4*)s_)[1];                 \
      RO2 = ((const f32x4*)s_)[2]; RO3 = ((const f32x4*)s_)[3];                 \
    }                                                                           \
    MEMFENCE;                                                                   \
    /* gates MFMA: A bf16 frags from abuf(CUR), B from Breg */                  \
    {                                                                           \
      const char* ab = lds + (CUR) * 16384;                                     \
      _Pragma("unroll")                                                         \
      for (int ks = 0; ks < 8; ++ks) {                                          \
        bf16x8 af0 = *(const bf16x8*)(ab + ks * 1024 + ((lane * 16) ^ (ks << 4)));       \
        bf16x8 af1 = *(const bf16x8*)(ab + (8 + ks) * 1024 + ((lane * 16) ^ (ks << 4))); \
        _Pragma("unroll")                                                       \
        for (int g_ = 0; g_ < 4; ++g_) {                                        \
          acc[0][g_] = __builtin_amdgcn_mfma_f32_16x16x32_bf16(af0, Breg[ks][g_], acc[0][g_], 0, 0, 0); \
          acc[1][g_] = __builtin_amdgcn_mfma_f32_16x16x32_bf16(af1, Breg[ks][g_], acc[1][g_], 0, 0, 0); \
        }                                                                       \
      }                                                                         \
    }                                                                           \
    MEMFENCE;                                                                   \
    /* Wch frags from L2 (consumed after barrier; elementwise covers latency) */\
    bf16x8 wf0 = *(const bf16x8*)(WchF + (size_t)((0 * 8 + wn) * 512 + lane * 8));  \
    bf16x8 wf1 = *(const bf16x8*)(WchF + (size_t)((1 * 8 + wn) * 512 + lane * 8));  \
    bf16x8 wf2 = *(const bf16x8*)(WchF + (size_t)((2 * 8 + wn) * 512 + lane * 8));  \
    bf16x8 wf3 = *(const bf16x8*)(WchF + (size_t)((3 * 8 + wn) * 512 + lane * 8));  \
    MEMFENCE;                                                                   \
    /* elementwise: c from cbuf(CUR); c_new -> global + c_ex(CUR) */            \
    {                                                                           \
      char* cexb = lds + 65536 + (CUR) * 8192;                                  \
      const char* cbr = lds + 32768 + (CUR) * 16384;                            \
      _Pragma("unroll")                                                         \
      for (int am = 0; am < 2; ++am)                                            \
        _Pragma("unroll")                                                       \
        for (int r = 0; r < 4; ++r) {                                           \
          float cval = *(const float*)(cbr + (((am * 16 + lg * 4 + r) * 128) + colc) * 4); \
          float f_  = fsig(acc[am][0][r] + bfb);                                \
          float i_  = fsig(acc[am][1][r] + bib);                                \
          float ct_ = ftanh(acc[am][2][r] + bcb);                               \
          float cv_ = f_ * cval + i_ * ct_;                                     \
          coutp[(m0 + am * 16 + lg * 4 + r) * 128 + colc] = cv_;                \
          *(unsigned short*)(cexb + (am * 4 + (wn >> 1)) * 1024                 \
               + (cslotbase + lg * 4 + r) * 16 + (l15 & 7) * 2) = f2bf(cv_);    \
        }                                                                       \
    }                                                                           \
    /* cvt RI (A for T+1, loaded a full tile ago) -> abuf(CUR^1) */             \
    if ((T) < 31) {                                                             \
      char* fb = lds + ((CUR) ^ 1) * 16384;                                     \
      *(bf16x8*)(fb + aoff0) = cvt8(RI0, RI1);                                  \
      *(bf16x8*)(fb + aoff1) = cvt8(RI2, RI3);                                  \
    }                                                                           \
    /* barrier: retire c-DMA; keep A(4)+Wch(4)+c-stores(8) in flight */         \
    asm volatile("s_waitcnt lgkmcnt(0) vmcnt(16)" ::: "memory");                \
    __builtin_amdgcn_s_barrier();                                               \
    __builtin_amdgcn_sched_barrier(0);                                          \
    /* GEMM2 (c_ex x wf) + h epilogue */                                        \
    {                                                                           \
      const char* cexr = lds + 65536 + (CUR) * 8192;                            \
      f32x4 acc2_0 = {0.f,0.f,0.f,0.f}, acc2_1 = {0.f,0.f,0.f,0.f};             \
      bf16x8 p0, p1;                                                            \
      p0 = *(const bf16x8*)(cexr + 0 * 1024 + lane * 16);                       \
      p1 = *(const bf16x8*)(cexr + 4 * 1024 + lane * 16);                       \
      acc2_0 = __builtin_amdgcn_mfma_f32_16x16x32_bf16(p0, wf0, acc2_0, 0, 0, 0); \
      acc2_1 = __builtin_amdgcn_mfma_f32_16x16x32_bf16(p1, wf0, acc2_1, 0, 0, 0); \
      p0 = *(const bf16x8*)(cexr + 1 * 1024 + lane * 16);                       \
      p1 = *(const bf16x8*)(cexr + 5 * 1024 + lane * 16);                       \
      acc2_0 = __builtin_amdgcn_mfma_f32_16x16x32_bf16(p0, wf1, acc2_0, 0, 0, 0); \
      acc2_1 = __builtin_amdgcn_mfma_f32_16x16x32_bf16(p1, wf1, acc2_1, 0, 0, 0); \
      p0 = *(const bf16x8*)(cexr + 2 * 1024 + lane * 16);                       \
      p1 = *(const bf16x8*)(cexr + 6 * 1024 + lane * 16);                       \
      acc2_0 = __builtin_amdgcn_mfma_f32_16x16x32_bf16(p0, wf2, acc2_0, 0, 0, 0); \
      acc2_1 = __builtin_amdgcn_mfma_f32_16x16x32_bf16(p1, wf2, acc2_1, 0, 0, 0); \
      p0 = *(const bf16x8*)(cexr + 3 * 1024 + lane * 16);                       \
      p1 = *(const bf16x8*)(cexr + 7 * 1024 + lane * 16);                       \
      acc2_0 = __builtin_amdgcn_mfma_f32_16x16x32_bf16(p0, wf3, acc2_0, 0, 0, 0); \
      acc2_1 = __builtin_amdgcn_mfma_f32_16x16x32_bf16(p1, wf3, acc2_1, 0, 0, 0); \
      _Pragma("unroll")                                                         \
      for (int r = 0; r < 4; ++r) {                                             \
        float o0 = fsig(acc[0][3][r] + bob);                                    \
        houtp[(m0 +      lg * 4 + r) * 128 + colc] = o0 * ftanh(acc2_0[r] + bchb); \
        float o1 = fsig(acc[1][3][r] + bob);                                    \
        houtp[(m0 + 16 + lg * 4 + r) * 128 + colc] = o1 * ftanh(acc2_1[r] + bchb); \
      }                                                                         \
    }                                                                           \
    _Pragma("unroll")                                                           \
    for (int am = 0; am < 2; ++am)                                              \
      _Pragma("unroll")                                                         \
      for (int g_ = 0; g_ < 4; ++g_) acc[am][g_] = (f32x4){0.f,0.f,0.f,0.f};    \
  } while (0)

// ---------------- fused kernel: 1024 rows per 512-thread block, 32-row tiles ----
// LDS (80 KB): A bf16 dbuf [0,16K)+[16K,32K); c fp32 dbuf [32K,48K)+[48K,64K);
//              c_ex dbuf [64K,72K)+[72K,80K)
__global__ __launch_bounds__(512, 2) void lstm_fused(
    const float* __restrict__ xg, const float* __restrict__ hg, const float* __restrict__ cg,
    const float* __restrict__ bfv, const float* __restrict__ biv,
    const float* __restrict__ bcv, const float* __restrict__ bov,
    const float* __restrict__ bchv,
    const unsigned short* __restrict__ WgF, const unsigned short* __restrict__ WchF,
    float* __restrict__ out, int nrows)
{
    __shared__ uint4 lds4[5120];                 // 80 KB
    char* lds = (char*)lds4;

    const int tid  = threadIdx.x;
    const int lane = tid & 63;
    const int wn   = tid >> 6;                   // 0..7: owns cols wn*16..+16 of each gate
    const int l15  = lane & 15;
    const int lg   = lane >> 4;
    const long base = (long)blockIdx.x << 10;    // 1024 rows per block

    float* houtp = out;
    float* coutp = out + (size_t)nrows * 128;

    const int colc = wn * 16 + l15;              // lane-local output column
    const float bfb = bfv[colc], bib = biv[colc], bcb = bcv[colc],
                bob = bov[colc], bchb = bchv[colc];
    const int cslotbase = ((wn & 1) * 2 + (l15 >> 3)) * 16;

    // ---- weights into registers (L2-resident source; read once per block)
    bf16x8 Breg[8][4];                           // [ks][gate] : 128 VGPRs
#pragma unroll
    for (int ks = 0; ks < 8; ++ks)
#pragma unroll
        for (int g = 0; g < 4; ++g)
            Breg[ks][g] = *(const bf16x8*)(WgF + (size_t)((ks * 32 + wn * 4 + g) * 512 + lane * 8));

    // ---- A-staging thread coords (thread stages 16 k-elems of one row)
    const int rowA = tid >> 4;                   // 0..31
    const int kgA  = tid & 15;                   // 16-elem k-group
    const int ksA  = kgA >> 1;
    const int lgA  = (kgA & 1) * 2;
    const int amA  = rowA >> 4;
    const int l15A = rowA & 15;
    const int aoff0 = (amA * 8 + ksA) * 1024 + ((((lgA    ) * 16 + l15A) * 16) ^ (ksA << 4));
    const int aoff1 = (amA * 8 + ksA) * 1024 + ((((lgA + 1) * 16 + l15A) * 16) ^ (ksA << 4));
    const float* asrc = (kgA < 8) ? (xg + kgA * 16) : (hg + (kgA - 8) * 16);

    // ---- prologue: c(0) DMA -> cbuf0 (first vm ops), A(0) -> cvt -> abuf0,
    //      A(1) -> RI. Explicit wait retires c-DMA + A(0); A(1) stays in flight.
    gload16(cg + (base + (tid >> 5)) * 128 + (tid & 31) * 4, lds + 32768 + tid * 16);
    gload16(cg + (base + 16 + (tid >> 5)) * 128 + (tid & 31) * 4, lds + 32768 + 8192 + tid * 16);
    MEMFENCE;
    {
        const float* s = asrc + (base + rowA) * 128;
        f32x4 v0 = ((const f32x4*)s)[0], v1 = ((const f32x4*)s)[1],
              v2 = ((const f32x4*)s)[2], v3 = ((const f32x4*)s)[3];
        *(bf16x8*)(lds + aoff0) = cvt8(v0, v1);
        *(bf16x8*)(lds + aoff1) = cvt8(v2, v3);
    }
    MEMFENCE;
    f32x4 rA0, rA1, rA2, rA3, rB0, rB1, rB2, rB3;
    {
        const float* s = asrc + (base + 32 + rowA) * 128;
        rA0 = ((const f32x4*)s)[0]; rA1 = ((const f32x4*)s)[1];
        rA2 = ((const f32x4*)s)[2]; rA3 = ((const f32x4*)s)[3];
    }
    asm volatile("s_waitcnt lgkmcnt(0) vmcnt(4)" ::: "memory");
    __builtin_amdgcn_s_barrier();

    f32x4 acc[2][4];                             // [am][gate]
#pragma unroll
    for (int am = 0; am < 2; ++am)
#pragma unroll
        for (int g = 0; g < 4; ++g) acc[am][g] = {0.f, 0.f, 0.f, 0.f};

#pragma unroll 1
    for (int t = 0; t < 32; t += 2) {
        TILE_BODY(t,     0, rA0,rA1,rA2,rA3, rB0,rB1,rB2,rB3);
        TILE_BODY(t + 1, 1, rB0,rB1,rB2,rB3, rA0,rA1,rA2,rA3);
    }
}

extern "C" void kernel_launch(void* const* d_in, const int* in_sizes, int n_in,
                              void* d_out, int out_size, void* d_ws, size_t ws_size,
                              hipStream_t stream)
{
    const float* x   = (const float*)d_in[0];
    const float* h   = (const float*)d_in[1];
    const float* c   = (const float*)d_in[2];
    const float* Wf  = (const float*)d_in[3];
    const float* bf_ = (const float*)d_in[4];
    const float* Wi  = (const float*)d_in[5];
    const float* bi_ = (const float*)d_in[6];
    const float* Wc  = (const float*)d_in[7];
    const float* bc_ = (const float*)d_in[8];
    const float* Wo  = (const float*)d_in[9];
    const float* bo_ = (const float*)d_in[10];
    const float* Wch = (const float*)d_in[11];
    const float* bch = (const float*)d_in[12];

    unsigned short* WgF  = (unsigned short*)d_ws;         // 512*256 bf16 fragment-linear
    unsigned short* WchF = WgF + 512 * 256;               // 128*128 bf16 fragment-linear
    float* out = (float*)d_out;

    int nrows = in_sizes[0] / 128;                        // 262144

    prep_weights<<<dim3(72), dim3(256), 0, stream>>>(Wf, Wi, Wc, Wo, Wch, WgF, WchF);
    lstm_fused<<<dim3(nrows / 1024), dim3(512), 0, stream>>>(
        x, h, c, bf_, bi_, bc_, bo_, bch, WgF, WchF, out, nrows);
}

// Round 12
// 144.703 us; speedup vs baseline: 2.0294x; 1.4849x over previous
//
#include <hip/hip_runtime.h>
#include <hip/hip_bf16.h>

// LSTM block, fused. Inputs fp32, outputs fp32. bf16 MFMA internally.
// r7 skeleton (weights-in-regs Breg 128/wave + Wreg 16, gate-interleaved
// lane-local elementwise, ONE counted barrier per 32-row tile) with ALL
// prefetch state in LDS via global_load_lds DMA (zero register cost):
//   A(t+2): 4 DMA ops -> fp32 landing dbuf (2x32K), consumed by a shared
//           cvt-pass (fp32->bf16 frags, r7 layout) one tile later.
//   c(t+1): 2 DMA ops -> fp32 dbuf (2x16K), consumed by elementwise.
// Barrier: s_waitcnt lgkmcnt(0) vmcnt(12); mid-body vmcnt(22) guards cvt-pass.
// LDS 144K: abuf bf16 2x16K | land fp32 2x32K | clds 2x16K | c_ex 2x8K.

typedef __attribute__((ext_vector_type(8))) short bf16x8;   // 8 bf16 = 4 VGPRs
typedef __attribute__((ext_vector_type(4))) float f32x4;

#define AB0   0
#define AB1   16384
#define LAND0 32768
#define LAND1 65536
#define CLDS0 98304
#define CLDS1 114688
#define CEX0  131072
#define CEX1  139264

static __device__ __forceinline__ unsigned short f2bf(float f) {
    unsigned int u = __builtin_bit_cast(unsigned int, f);
    u += 0x7FFFu + ((u >> 16) & 1u);      // RNE
    return (unsigned short)(u >> 16);
}

static __device__ __forceinline__ unsigned int cvtpk(float lo, float hi) {
    unsigned int r;
    asm("v_cvt_pk_bf16_f32 %0, %1, %2" : "=v"(r) : "v"(lo), "v"(hi));
    return r;
}

static __device__ __forceinline__ bf16x8 cvt8(f32x4 a, f32x4 b) {
    union { bf16x8 v; unsigned int w[4]; } r;
    r.w[0] = cvtpk(a[0], a[1]);
    r.w[1] = cvtpk(a[2], a[3]);
    r.w[2] = cvtpk(b[0], b[1]);
    r.w[3] = cvtpk(b[2], b[3]);
    return r.v;
}

static __device__ __forceinline__ float fsig(float x) {
    float e = __builtin_amdgcn_exp2f(-1.44269504f * x);
    return __builtin_amdgcn_rcpf(1.0f + e);
}
static __device__ __forceinline__ float ftanh(float x) {
    float e = __builtin_amdgcn_exp2f(2.8853900818f * x);
    return 1.0f - 2.0f * __builtin_amdgcn_rcpf(e + 1.0f);
}

static __device__ __forceinline__ void gload16(const void* gsrc, void* ldst) {
    __builtin_amdgcn_global_load_lds(
        (const __attribute__((address_space(1))) unsigned int*)gsrc,
        (__attribute__((address_space(3))) unsigned int*)ldst,
        16, 0, 0);
}

#define MEMFENCE asm volatile("" ::: "memory")

// ---------------- weight prep: fragment-linear bf16, 16-col gate interleave ----
__global__ void prep_weights(const float* __restrict__ Wf, const float* __restrict__ Wi,
                             const float* __restrict__ Wc, const float* __restrict__ Wo,
                             const float* __restrict__ Wch,
                             unsigned short* __restrict__ WgF,   // 512*256
                             unsigned short* __restrict__ WchF)  // 128*128
{
    int u = blockIdx.x * 256 + threadIdx.x;
    if (u < 16384) {
        int lane = u & 63, g = (u >> 6) & 3, wn = (u >> 8) & 7, ks = u >> 11;
        int l15 = lane & 15, lg = lane >> 4;
        int cg = wn * 16 + l15;
        int k0 = ks * 32 + lg * 8;
        const float* W = (g == 0) ? Wf : (g == 1) ? Wi : (g == 2) ? Wc : Wo;
        union { bf16x8 v; unsigned short s[8]; } r;
#pragma unroll
        for (int i = 0; i < 8; ++i) r.s[i] = f2bf(W[(size_t)(k0 + i) * 128 + cg]);
        *(bf16x8*)(WgF + (size_t)u * 8) = r.v;
    } else if (u < 16384 + 2048) {
        int u2 = u - 16384;
        int lane = u2 & 63, wn = (u2 >> 6) & 7, kt = u2 >> 9;
        int l15 = lane & 15, lg = lane >> 4;
        int col = wn * 16 + l15, k0 = kt * 32 + lg * 8;
        union { bf16x8 v; unsigned short s[8]; } r;
#pragma unroll
        for (int i = 0; i < 8; ++i) r.s[i] = f2bf(Wch[(size_t)(k0 + i) * 128 + col]);
        *(bf16x8*)(WchF + (size_t)u2 * 8) = r.v;
    }
}

// One 32-row tile. CUR = compile-time parity (t & 1).
#define TILE_BODY(T, CUR)                                                       \
  do {                                                                          \
    const long m0 = base + (long)(T) * 32;                                      \
    /* c-DMA(t+1) -> clds[CUR^1]  (2 ops) */                                    \
    if ((T) < 31) {                                                             \
      char* cd = lds + ((CUR) ? CLDS0 : CLDS1);                                 \
      gload16(cg + (m0 + 32 + (tid >> 5)) * 128 + (tid & 31) * 4, cd + tid * 16);        \
      gload16(cg + (m0 + 48 + (tid >> 5)) * 128 + (tid & 31) * 4, cd + 8192 + tid * 16); \
    }                                                                           \
    MEMFENCE;                                                                   \
    /* A-DMA(t+2) -> land[CUR]  (4 ops; dummy at T==30 keeps counts) */         \
    if ((T) < 31) {                                                             \
      const long ar = ((T) < 30) ? (m0 + 64) : m0;                              \
      char* ad = lds + ((CUR) ? LAND1 : LAND0) + wn * 1024 + lane * 16;         \
      _Pragma("unroll")                                                         \
      for (int j = 0; j < 4; ++j)                                               \
        gload16(dmaA + (ar + wn + j * 8) * 128, ad + j * 8192);                 \
    }                                                                           \
    MEMFENCE;                                                                   \
    /* GEMM1: A bf16 frags from abuf[CUR], B from Breg */                       \
    {                                                                           \
      const char* ab = lds + ((CUR) ? AB1 : AB0);                               \
      _Pragma("unroll")                                                         \
      for (int ks = 0; ks < 8; ++ks) {                                          \
        bf16x8 af0 = *(const bf16x8*)(ab + ks * 1024 + ((lane * 16) ^ (ks << 4)));       \
        bf16x8 af1 = *(const bf16x8*)(ab + (8 + ks) * 1024 + ((lane * 16) ^ (ks << 4))); \
        _Pragma("unroll")                                                       \
        for (int g_ = 0; g_ < 4; ++g_) {                                        \
          acc[0][g_] = __builtin_amdgcn_mfma_f32_16x16x32_bf16(af0, Breg[ks][g_], acc[0][g_], 0, 0, 0); \
          acc[1][g_] = __builtin_amdgcn_mfma_f32_16x16x32_bf16(af1, Breg[ks][g_], acc[1][g_], 0, 0, 0); \
        }                                                                       \
      }                                                                         \
    }                                                                           \
    /* elementwise: c from clds[CUR]; c_new -> global + c_ex[CUR] */            \
    {                                                                           \
      char* cexb = lds + ((CUR) ? CEX1 : CEX0);                                 \
      const char* cbr = lds + ((CUR) ? CLDS1 : CLDS0);                          \
      _Pragma("unroll")                                                         \
      for (int am = 0; am < 2; ++am)                                            \
        _Pragma("unroll")                                                       \
        for (int r = 0; r < 4; ++r) {                                           \
          float cval = *(const float*)(cbr + (am * 16 + lg * 4 + r) * 512 + colc * 4); \
          float f_  = fsig(acc[am][0][r] + bfb);                                \
          float i_  = fsig(acc[am][1][r] + bib);                                \
          float ct_ = ftanh(acc[am][2][r] + bcb);                               \
          float cv_ = f_ * cval + i_ * ct_;                                     \
          coutp[(m0 + am * 16 + lg * 4 + r) * 128 + colc] = cv_;                \
          *(unsigned short*)(cexb + (am * 4 + (wn >> 1)) * 1024                 \
               + (cslotbase + lg * 4 + r) * 16 + (l15 & 7) * 2) = f2bf(cv_);    \
        }                                                                       \
    }                                                                           \
    MEMFENCE;                                                                   \
    /* cvt-pass: land[CUR^1] (A for t+1, DMA'd a full tile ago) -> abuf[CUR^1] */ \
    if ((T) < 31) {                                                             \
      asm volatile("s_waitcnt vmcnt(22)" ::: "memory");                         \
      const char* ln = lds + ((CUR) ? LAND0 : LAND1) + rowA * 1024;             \
      f32x4 q0 = *(const f32x4*)(ln + (((kgA * 4 + 0) ^ swzA) << 4));           \
      f32x4 q1 = *(const f32x4*)(ln + (((kgA * 4 + 1) ^ swzA) << 4));           \
      f32x4 q2 = *(const f32x4*)(ln + (((kgA * 4 + 2) ^ swzA) << 4));           \
      f32x4 q3 = *(const f32x4*)(ln + (((kgA * 4 + 3) ^ swzA) << 4));           \
      char* fb = lds + ((CUR) ? AB0 : AB1);                                     \
      *(bf16x8*)(fb + aoff0) = cvt8(q0, q1);                                    \
      *(bf16x8*)(fb + aoff1) = cvt8(q2, q3);                                    \
    }                                                                           \
    /* ONE barrier: retire c-DMA(t+1)+older; keep A-DMA(t+2)+stores in flight */\
    asm volatile("s_waitcnt lgkmcnt(0) vmcnt(12)" ::: "memory");                \
    __builtin_amdgcn_s_barrier();                                               \
    __builtin_amdgcn_sched_barrier(0);                                          \
    /* GEMM2 (c_ex[CUR] x Wreg) + h epilogue */                                 \
    {                                                                           \
      const char* cexr = lds + ((CUR) ? CEX1 : CEX0);                           \
      f32x4 acc2_0 = {0.f,0.f,0.f,0.f}, acc2_1 = {0.f,0.f,0.f,0.f};             \
      _Pragma("unroll")                                                         \
      for (int kt = 0; kt < 4; ++kt) {                                          \
        bf16x8 p0 = *(const bf16x8*)(cexr + kt * 1024 + lane * 16);             \
        bf16x8 p1 = *(const bf16x8*)(cexr + (4 + kt) * 1024 + lane * 16);       \
        acc2_0 = __builtin_amdgcn_mfma_f32_16x16x32_bf16(p0, Wreg[kt], acc2_0, 0, 0, 0); \
        acc2_1 = __builtin_amdgcn_mfma_f32_16x16x32_bf16(p1, Wreg[kt], acc2_1, 0, 0, 0); \
      }                                                                         \
      _Pragma("unroll")                                                         \
      for (int r = 0; r < 4; ++r) {                                             \
        float o0 = fsig(acc[0][3][r] + bob);                                    \
        houtp[(m0 +      lg * 4 + r) * 128 + colc] = o0 * ftanh(acc2_0[r] + bchb); \
        float o1 = fsig(acc[1][3][r] + bob);                                    \
        houtp[(m0 + 16 + lg * 4 + r) * 128 + colc] = o1 * ftanh(acc2_1[r] + bchb); \
      }                                                                         \
    }                                                                           \
    _Pragma("unroll")                                                           \
    for (int am = 0; am < 2; ++am)                                              \
      _Pragma("unroll")                                                         \
      for (int g_ = 0; g_ < 4; ++g_) acc[am][g_] = (f32x4){0.f,0.f,0.f,0.f};    \
  } while (0)

// ---------------- fused kernel: 1024 rows per 512-thread block, 32-row tiles ----
__global__ __launch_bounds__(512, 2) void lstm_fused(
    const float* __restrict__ xg, const float* __restrict__ hg, const float* __restrict__ cg,
    const float* __restrict__ bfv, const float* __restrict__ biv,
    const float* __restrict__ bcv, const float* __restrict__ bov,
    const float* __restrict__ bchv,
    const unsigned short* __restrict__ WgF, const unsigned short* __restrict__ WchF,
    float* __restrict__ out, int nrows)
{
    __shared__ uint4 lds4[9216];                 // 144 KB
    char* lds = (char*)lds4;

    const int tid  = threadIdx.x;
    const int lane = tid & 63;
    const int wn   = tid >> 6;                   // wave id = col-group = A-row class (mod 8)
    const int l15  = lane & 15;
    const int lg   = lane >> 4;
    const long base = (long)blockIdx.x << 10;    // 1024 rows per block

    float* houtp = out;
    float* coutp = out + (size_t)nrows * 128;

    const int colc = wn * 16 + l15;              // lane-local output column
    const float bfb = bfv[colc], bib = biv[colc], bcb = bcv[colc],
                bob = bov[colc], bchb = bchv[colc];
    const int cslotbase = ((wn & 1) * 2 + (l15 >> 3)) * 16;

    // ---- weights into registers (L2-resident source; read once per block)
    bf16x8 Breg[8][4];                           // [ks][gate] : 128 VGPRs
#pragma unroll
    for (int ks = 0; ks < 8; ++ks)
#pragma unroll
        for (int g = 0; g < 4; ++g)
            Breg[ks][g] = *(const bf16x8*)(WgF + (size_t)((ks * 32 + wn * 4 + g) * 512 + lane * 8));
    bf16x8 Wreg[4];                              // [kt] : 16 VGPRs
#pragma unroll
    for (int kt = 0; kt < 4; ++kt)
        Wreg[kt] = *(const bf16x8*)(WchF + (size_t)((kt * 8 + wn) * 512 + lane * 8));

    // ---- A-DMA source: lane stages 16B unit gu = lane ^ wn of each row
    //      (rows wv+8j: row&7 == wn) -> LDS[row][u] = G[row][u ^ (row&7)]
    const int gu = lane ^ wn;
    const float* dmaA = ((gu < 32) ? (xg + gu * 4) : (hg + (gu - 32) * 4));

    // ---- cvt-pass thread coords (thread converts 16 k-elems of one row)
    const int rowA = tid >> 4;                   // 0..31
    const int kgA  = tid & 15;                   // 16-elem k-group
    const int swzA = rowA & 7;
    const int ksA  = kgA >> 1;
    const int lgA  = (kgA & 1) * 2;
    const int amA  = rowA >> 4;
    const int l15A = rowA & 15;
    const int aoff0 = (amA * 8 + ksA) * 1024 + ((((lgA    ) * 16 + l15A) * 16) ^ (ksA << 4));
    const int aoff1 = (amA * 8 + ksA) * 1024 + ((((lgA + 1) * 16 + l15A) * 16) ^ (ksA << 4));
    const float* asrc = (kgA < 8) ? (xg + kgA * 16) : (hg + (kgA - 8) * 16);

    // ---- prologue: c(0) DMA -> clds0; A(1) DMA -> land1; A(0) direct -> abuf0
    gload16(cg + (base + (tid >> 5)) * 128 + (tid & 31) * 4, lds + CLDS0 + tid * 16);
    gload16(cg + (base + 16 + (tid >> 5)) * 128 + (tid & 31) * 4, lds + CLDS0 + 8192 + tid * 16);
    MEMFENCE;
    {
        char* ad = lds + LAND1 + wn * 1024 + lane * 16;
#pragma unroll
        for (int j = 0; j < 4; ++j)
            gload16(dmaA + (base + 32 + wn + j * 8) * 128, ad + j * 8192);
    }
    MEMFENCE;
    {
        const float* s = asrc + (base + rowA) * 128;
        f32x4 v0 = ((const f32x4*)s)[0], v1 = ((const f32x4*)s)[1],
              v2 = ((const f32x4*)s)[2], v3 = ((const f32x4*)s)[3];
        *(bf16x8*)(lds + AB0 + aoff0) = cvt8(v0, v1);
        *(bf16x8*)(lds + AB0 + aoff1) = cvt8(v2, v3);
    }
    asm volatile("s_waitcnt lgkmcnt(0) vmcnt(0)" ::: "memory");
    __builtin_amdgcn_s_barrier();

    f32x4 acc[2][4];                             // [am][gate]
#pragma unroll
    for (int am = 0; am < 2; ++am)
#pragma unroll
        for (int g = 0; g < 4; ++g) acc[am][g] = {0.f, 0.f, 0.f, 0.f};

#pragma unroll 1
    for (int t = 0; t < 32; t += 2) {
        TILE_BODY(t,     0);
        TILE_BODY(t + 1, 1);
    }
}

extern "C" void kernel_launch(void* const* d_in, const int* in_sizes, int n_in,
                              void* d_out, int out_size, void* d_ws, size_t ws_size,
                              hipStream_t stream)
{
    const float* x   = (const float*)d_in[0];
    const float* h   = (const float*)d_in[1];
    const float* c   = (const float*)d_in[2];
    const float* Wf  = (const float*)d_in[3];
    const float* bf_ = (const float*)d_in[4];
    const float* Wi  = (const float*)d_in[5];
    const float* bi_ = (const float*)d_in[6];
    const float* Wc  = (const float*)d_in[7];
    const float* bc_ = (const float*)d_in[8];
    const float* Wo  = (const float*)d_in[9];
    const float* bo_ = (const float*)d_in[10];
    const float* Wch = (const float*)d_in[11];
    const float* bch = (const float*)d_in[12];

    unsigned short* WgF  = (unsigned short*)d_ws;         // 512*256 bf16 fragment-linear
    unsigned short* WchF = WgF + 512 * 256;               // 128*128 bf16 fragment-linear
    float* out = (float*)d_out;

    int nrows = in_sizes[0] / 128;                        // 262144

    prep_weights<<<dim3(72), dim3(256), 0, stream>>>(Wf, Wi, Wc, Wo, Wch, WgF, WchF);
    lstm_fused<<<dim3(nrows / 1024), dim3(512), 0, stream>>>(
        x, h, c, bf_, bi_, bc_, bo_, bch, WgF, WchF, out, nrows);
}